// Round 12
// baseline (49.020 us; speedup 1.0000x reference)
//
#include <hip/hip_runtime.h>

#define NB 8
#define NT 2048
#define NC 1024
#define NH 64

typedef __bf16 bf16x8 __attribute__((ext_vector_type(8)));
typedef float f32x4 __attribute__((ext_vector_type(4)));

static __device__ __forceinline__ float4 ldf4(const float* p) {
  return *reinterpret_cast<const float4*>(p);
}
static __device__ __forceinline__ bf16x8 ldb8(const __bf16* p) {
  return *reinterpret_cast<const bf16x8*>(p);
}
static __device__ __forceinline__ unsigned pack_bf2(float a, float b) {
  unsigned short ua = __builtin_bit_cast(unsigned short, (__bf16)a);
  unsigned short ub = __builtin_bit_cast(unsigned short, (__bf16)b);
  return (unsigned)ua | ((unsigned)ub << 16);
}

// ---------------------------------------------------------------------------
// Kernel A: Wt[192][1024] bf16 = transpose+convert of Wq|Wk|Wv (fp32 [1024][64]).
// ---------------------------------------------------------------------------
__global__ __launch_bounds__(256) void wt_kernel(
    const float* __restrict__ Wq, const float* __restrict__ Wk,
    const float* __restrict__ Wv, __bf16* __restrict__ wt) {
  __shared__ __bf16 tl[64][72];
  const int tid = threadIdx.x;
  const int mat = blockIdx.x >> 4;
  const int k0 = (blockIdx.x & 15) * 64;
  const float* W = (mat == 0) ? Wq : (mat == 1) ? Wk : Wv;
#pragma unroll
  for (int it = 0; it < 4; ++it) {
    int f = tid + it * 256;
    int kk = f >> 4, c4 = (f & 15) * 4;
    float4 w = ldf4(&W[(k0 + kk) * NH + c4]);
    tl[c4 + 0][kk] = (__bf16)w.x;
    tl[c4 + 1][kk] = (__bf16)w.y;
    tl[c4 + 2][kk] = (__bf16)w.z;
    tl[c4 + 3][kk] = (__bf16)w.w;
  }
  __syncthreads();
#pragma unroll
  for (int it = 0; it < 2; ++it) {
    int f = tid + it * 256;
    int h = f >> 3, k8 = (f & 7) * 8;
    *reinterpret_cast<bf16x8*>(&wt[(mat * 64 + h) * NC + k0 + k8]) =
        *reinterpret_cast<const bf16x8*>(&tl[h][k8]);
  }
}

// ---------------------------------------------------------------------------
// Kernel B: q,k (bf16 row-major) and v^T (bf16 [b][h][t]) = x @ W via MFMA.
// R4 champion skeleton with BK=128: 8 staging phases (was 16), 24 MFMAs per
// wave per phase (was 12). Empirical phase-wall ~2.3us/phase across all
// tried structures -> halving phases is the lever. Single-buffered LDS
// As[32][136] + Bs[192][136] (pad+8: proven 2-way-free banks); vls for the
// v-transpose ALIASES the same smem (only used after the K loop, barrier-
// separated). 512 blocks x 256 thr (4 waves), 2 blocks/CU (119 KB LDS/CU).
// Depth-1 reg prefetch, clamp-unconditional loads, 2 barriers per phase.
// ---------------------------------------------------------------------------
__global__ __launch_bounds__(256, 2) void qkv_mfma_kernel(
    const float* __restrict__ x, const __bf16* __restrict__ wt,
    __bf16* __restrict__ qb, __bf16* __restrict__ kb, __bf16* __restrict__ vt) {
  __shared__ __align__(16) char smem[60928];
  __bf16(*As)[136] = reinterpret_cast<__bf16(*)[136]>(smem);          // [32][136]
  __bf16(*Bs)[136] = reinterpret_cast<__bf16(*)[136]>(smem + 8704);   // [192][136]
  __bf16(*vls)[40] = reinterpret_cast<__bf16(*)[40]>(smem);           // [64][40] alias
  const int tid = threadIdx.x;
  const int lane = tid & 63;
  const int w = tid >> 6;          // 0..3
  const int row0 = blockIdx.x * 32;
  const int csub = w * 48;
  const int l15 = lane & 15, lg = lane >> 4;

  f32x4 acc[2][3];
#pragma unroll
  for (int i = 0; i < 2; ++i)
#pragma unroll
    for (int j = 0; j < 3; ++j) acc[i][j] = (f32x4){0.f, 0.f, 0.f, 0.f};

  // staging thread->tile mapping: A 4 float4 (32 rows x 128 k fp32),
  // B 12 bf16x8 (192 cols x 128 k bf16)
  int arr[4], ark[4];
#pragma unroll
  for (int it = 0; it < 4; ++it) {
    int f = tid + it * 256;
    arr[it] = f >> 5;          // 0..31
    ark[it] = (f & 31) * 4;    // 0..124
  }
  int bcol[12], bk8[12];
#pragma unroll
  for (int it = 0; it < 12; ++it) {
    int f = tid + it * 256;
    bcol[it] = f >> 4;         // 0..191
    bk8[it] = (f & 15) * 8;    // 0..120
  }

  float4 sA[4];
  bf16x8 sB[12];
  // prologue: phase 0 loads
#pragma unroll
  for (int it = 0; it < 4; ++it)
    sA[it] = ldf4(&x[(row0 + arr[it]) * NC + ark[it]]);
#pragma unroll
  for (int it = 0; it < 12; ++it)
    sB[it] = ldb8(&wt[bcol[it] * NC + bk8[it]]);

  for (int ph = 0; ph < 8; ++ph) {
    // write staged regs to LDS
#pragma unroll
    for (int it = 0; it < 4; ++it) {
      uint2 u = {pack_bf2(sA[it].x, sA[it].y), pack_bf2(sA[it].z, sA[it].w)};
      *reinterpret_cast<uint2*>(&As[arr[it]][ark[it]]) = u;
    }
#pragma unroll
    for (int it = 0; it < 12; ++it)
      *reinterpret_cast<bf16x8*>(&Bs[bcol[it]][bk8[it]]) = sB[it];
    __syncthreads();
    // prefetch next phase (clamped, unconditional -> no load sinking)
    const int kn = ((ph + 1 < 8) ? ph + 1 : 7) * 128;
#pragma unroll
    for (int it = 0; it < 4; ++it)
      sA[it] = ldf4(&x[(row0 + arr[it]) * NC + kn + ark[it]]);
#pragma unroll
    for (int it = 0; it < 12; ++it)
      sB[it] = ldb8(&wt[bcol[it] * NC + kn + bk8[it]]);
    // compute: 4 k-steps x 6 MFMAs
#pragma unroll
    for (int kk = 0; kk < 4; ++kk) {
      bf16x8 af[2], bfr[3];
#pragma unroll
      for (int rt = 0; rt < 2; ++rt)
        af[rt] = ldb8(&As[rt * 16 + l15][kk * 32 + lg * 8]);
#pragma unroll
      for (int nt = 0; nt < 3; ++nt)
        bfr[nt] = ldb8(&Bs[csub + nt * 16 + l15][kk * 32 + lg * 8]);
#pragma unroll
      for (int rt = 0; rt < 2; ++rt)
#pragma unroll
        for (int nt = 0; nt < 3; ++nt)
          acc[rt][nt] = __builtin_amdgcn_mfma_f32_16x16x32_bf16(
              af[rt], bfr[nt], acc[rt][nt], 0, 0, 0);
    }
    __syncthreads();
  }

  // epilogue: D layout col=l15, row=lg*4+r. mat uniform per (w,nt).
  // vls aliases As/Bs -- all K-loop LDS reads are complete (barrier above).
#pragma unroll
  for (int rt = 0; rt < 2; ++rt) {
#pragma unroll
    for (int nt = 0; nt < 3; ++nt) {
      int colbase = csub + nt * 16;   // wave-uniform, multiple of 16
      int mat = colbase >> 6;
      int h = (colbase & 63) + l15;
      if (mat == 0) {
#pragma unroll
        for (int r = 0; r < 4; ++r) {
          int row = row0 + rt * 16 + lg * 4 + r;
          qb[row * NH + h] = (__bf16)(acc[rt][nt][r] * 0.125f);  // pre-scale q
        }
      } else if (mat == 1) {
#pragma unroll
        for (int r = 0; r < 4; ++r) {
          int row = row0 + rt * 16 + lg * 4 + r;
          kb[row * NH + h] = (__bf16)acc[rt][nt][r];
        }
      } else {
        ushort4 pk;
        pk.x = __builtin_bit_cast(unsigned short, (__bf16)acc[rt][nt][0]);
        pk.y = __builtin_bit_cast(unsigned short, (__bf16)acc[rt][nt][1]);
        pk.z = __builtin_bit_cast(unsigned short, (__bf16)acc[rt][nt][2]);
        pk.w = __builtin_bit_cast(unsigned short, (__bf16)acc[rt][nt][3]);
        *reinterpret_cast<ushort4*>(&vls[h][rt * 16 + lg * 4]) = pk;
      }
    }
  }
  __syncthreads();
  // cooperative coalesced v^T store: 64 h x 32 t, one 16B store per thread
  {
    int h = tid >> 2, t8 = (tid & 3) * 8;
    int bb = row0 >> 11;
    int t0l = row0 & (NT - 1);
    *reinterpret_cast<bf16x8*>(&vt[((size_t)bb * NH + h) * NT + t0l + t8]) =
        *reinterpret_cast<const bf16x8*>(&vls[h][t8]);
  }
}

// ---------------------------------------------------------------------------
// Kernel C: causal flash attention via MFMA, intra-block KV split.
// (exact R4 version) Grid dim3(64,8); qt = (y<4) ? 63-x : x. 4 waves;
// wave w handles KV chunks c = w, w+4, ... setprio(1) around MFMA clusters.
// ---------------------------------------------------------------------------
__global__ __launch_bounds__(256, 2) void attn_mfma_kernel(
    const __bf16* __restrict__ qb, const __bf16* __restrict__ kb,
    const __bf16* __restrict__ vt, float* __restrict__ out) {
  __shared__ __bf16 ps[4][32][72];
  __shared__ float obuf[4][32][68];
  __shared__ float msh[4][32], lsh[4][32];
  const int tid = threadIdx.x;
  const int lane = tid & 63;
  const int w = tid >> 6;
  const int l15 = lane & 15, lg = lane >> 4;
  const int b = blockIdx.y;
  const int qt = (blockIdx.y < 4) ? (63 - (int)blockIdx.x) : (int)blockIdx.x;
  const int q0 = qt * 32;
  const size_t bT = (size_t)b * NT;

  bf16x8 qf[2][2];
#pragma unroll
  for (int ct = 0; ct < 2; ++ct)
#pragma unroll
    for (int kh = 0; kh < 2; ++kh)
      qf[ct][kh] = *reinterpret_cast<const bf16x8*>(
          &qb[(bT + q0 + ct * 16 + l15) * NH + kh * 32 + lg * 8]);

  float m[2] = {-1e30f, -1e30f};
  float lsum[2] = {0.f, 0.f};
  f32x4 o[2][4];
#pragma unroll
  for (int i = 0; i < 2; ++i)
#pragma unroll
    for (int j = 0; j < 4; ++j) o[i][j] = (f32x4){0.f, 0.f, 0.f, 0.f};

  const int nch = qt / 2 + 1;
  bf16x8 kf[4][2], vf[4][2];
  if (w < nch) {
    const int s0 = w * 64;
#pragma unroll
    for (int st = 0; st < 4; ++st)
#pragma unroll
      for (int kh = 0; kh < 2; ++kh)
        kf[st][kh] = *reinterpret_cast<const bf16x8*>(
            &kb[(bT + s0 + st * 16 + l15) * NH + kh * 32 + lg * 8]);
#pragma unroll
    for (int ht = 0; ht < 4; ++ht)
#pragma unroll
      for (int sh = 0; sh < 2; ++sh)
        vf[ht][sh] = *reinterpret_cast<const bf16x8*>(
            &vt[((size_t)b * NH + ht * 16 + l15) * NT + s0 + sh * 32 + lg * 8]);
  }

  for (int c = w; c < nch; c += 4) {
    const int s0 = c * 64;
    f32x4 s[4][2];
#pragma unroll
    for (int st = 0; st < 4; ++st)
#pragma unroll
      for (int ct = 0; ct < 2; ++ct) s[st][ct] = (f32x4){0.f, 0.f, 0.f, 0.f};
    __builtin_amdgcn_s_setprio(1);
#pragma unroll
    for (int st = 0; st < 4; ++st)
#pragma unroll
      for (int ct = 0; ct < 2; ++ct)
#pragma unroll
        for (int kh = 0; kh < 2; ++kh)
          s[st][ct] = __builtin_amdgcn_mfma_f32_16x16x32_bf16(kf[st][kh], qf[ct][kh], s[st][ct], 0, 0, 0);
    __builtin_amdgcn_s_setprio(0);

    const int cn = c + 4;
    bf16x8 kfn[4][2], vfn[4][2];
    if (cn < nch) {
      const int sn = cn * 64;
#pragma unroll
      for (int st = 0; st < 4; ++st)
#pragma unroll
        for (int kh = 0; kh < 2; ++kh)
          kfn[st][kh] = *reinterpret_cast<const bf16x8*>(
              &kb[(bT + sn + st * 16 + l15) * NH + kh * 32 + lg * 8]);
#pragma unroll
      for (int ht = 0; ht < 4; ++ht)
#pragma unroll
        for (int sh = 0; sh < 2; ++sh)
          vfn[ht][sh] = *reinterpret_cast<const bf16x8*>(
              &vt[((size_t)b * NH + ht * 16 + l15) * NT + sn + sh * 32 + lg * 8]);
    }

    if (s0 + 63 > q0) {
#pragma unroll
      for (int st = 0; st < 4; ++st)
#pragma unroll
        for (int ct = 0; ct < 2; ++ct) {
          int qg = q0 + ct * 16 + l15;
#pragma unroll
          for (int r = 0; r < 4; ++r) {
            int sg = s0 + st * 16 + lg * 4 + r;
            if (sg > qg) s[st][ct][r] = -1e30f;
          }
        }
    }
    float scv[2];
#pragma unroll
    for (int ct = 0; ct < 2; ++ct) {
      float rmx = -1e30f;
#pragma unroll
      for (int st = 0; st < 4; ++st)
#pragma unroll
        for (int r = 0; r < 4; ++r) rmx = fmaxf(rmx, s[st][ct][r]);
      rmx = fmaxf(rmx, __shfl_xor(rmx, 16));
      rmx = fmaxf(rmx, __shfl_xor(rmx, 32));
      float mn = fmaxf(m[ct], rmx);
      float sc = __expf(m[ct] - mn);
      m[ct] = mn;
      float rs = 0.f;
#pragma unroll
      for (int st = 0; st < 4; ++st) {
        float p0 = __expf(s[st][ct][0] - mn);
        float p1 = __expf(s[st][ct][1] - mn);
        float p2 = __expf(s[st][ct][2] - mn);
        float p3 = __expf(s[st][ct][3] - mn);
        rs += (p0 + p1) + (p2 + p3);
        int sp = st * 16 + lg * 4;
        *reinterpret_cast<unsigned*>(&ps[w][ct * 16 + l15][sp]) = pack_bf2(p0, p1);
        *reinterpret_cast<unsigned*>(&ps[w][ct * 16 + l15][sp + 2]) = pack_bf2(p2, p3);
      }
      rs += __shfl_xor(rs, 16);
      rs += __shfl_xor(rs, 32);
      lsum[ct] = lsum[ct] * sc + rs;
      scv[ct] = sc;
    }
#pragma unroll
    for (int rt = 0; rt < 2; ++rt)
#pragma unroll
      for (int r = 0; r < 4; ++r) {
        float fsc = __shfl(scv[rt], lg * 4 + r, 64);
#pragma unroll
        for (int ht = 0; ht < 4; ++ht) o[rt][ht][r] *= fsc;
      }
    __builtin_amdgcn_s_setprio(1);
#pragma unroll
    for (int rt = 0; rt < 2; ++rt) {
      bf16x8 pf[2];
#pragma unroll
      for (int sh = 0; sh < 2; ++sh)
        pf[sh] = *reinterpret_cast<const bf16x8*>(&ps[w][rt * 16 + l15][sh * 32 + lg * 8]);
#pragma unroll
      for (int ht = 0; ht < 4; ++ht)
#pragma unroll
        for (int sh = 0; sh < 2; ++sh)
          o[rt][ht] = __builtin_amdgcn_mfma_f32_16x16x32_bf16(pf[sh], vf[ht][sh], o[rt][ht], 0, 0, 0);
    }
    __builtin_amdgcn_s_setprio(0);
    if (cn < nch) {
#pragma unroll
      for (int st = 0; st < 4; ++st)
#pragma unroll
        for (int kh = 0; kh < 2; ++kh) kf[st][kh] = kfn[st][kh];
#pragma unroll
      for (int ht = 0; ht < 4; ++ht)
#pragma unroll
        for (int sh = 0; sh < 2; ++sh) vf[ht][sh] = vfn[ht][sh];
    }
  }

  if (lg == 0) {
#pragma unroll
    for (int ct = 0; ct < 2; ++ct) {
      msh[w][ct * 16 + l15] = m[ct];
      lsh[w][ct * 16 + l15] = lsum[ct];
    }
  }
#pragma unroll
  for (int rt = 0; rt < 2; ++rt)
#pragma unroll
    for (int ht = 0; ht < 4; ++ht)
#pragma unroll
      for (int r = 0; r < 4; ++r)
        obuf[w][rt * 16 + lg * 4 + r][ht * 16 + l15] = o[rt][ht][r];
  __syncthreads();

  {
    int qr = tid >> 3, h8 = (tid & 7) * 8;
    float m0 = msh[0][qr], m1 = msh[1][qr], m2 = msh[2][qr], m3 = msh[3][qr];
    float M = fmaxf(fmaxf(m0, m1), fmaxf(m2, m3));
    float e0 = __expf(m0 - M), e1 = __expf(m1 - M);
    float e2 = __expf(m2 - M), e3 = __expf(m3 - M);
    float L = e0 * lsh[0][qr] + e1 * lsh[1][qr] + e2 * lsh[2][qr] + e3 * lsh[3][qr];
    float inv = 1.f / L;
#pragma unroll
    for (int i = 0; i < 8; ++i) {
      int h = h8 + i;
      float v = e0 * obuf[0][qr][h] + e1 * obuf[1][qr][h] +
                e2 * obuf[2][qr][h] + e3 * obuf[3][qr][h];
      out[(bT + q0 + qr) * NH + h] = v * inv;
    }
  }
}

extern "C" void kernel_launch(void* const* d_in, const int* in_sizes, int n_in,
                              void* d_out, int out_size, void* d_ws, size_t ws_size,
                              hipStream_t stream) {
  const float* x  = (const float*)d_in[0];
  const float* Wq = (const float*)d_in[1];
  const float* Wk = (const float*)d_in[2];
  const float* Wv = (const float*)d_in[3];
  float* out = (float*)d_out;

  char* ws = (char*)d_ws;
  __bf16* wt = (__bf16*)(ws);                        // 384 KB
  __bf16* qb = (__bf16*)(ws + 393216);               // 2 MB
  __bf16* kb = (__bf16*)(ws + 393216 + 2097152);     // 2 MB
  __bf16* vt = (__bf16*)(ws + 393216 + 2 * 2097152); // 2 MB

  wt_kernel<<<dim3(48), dim3(256), 0, stream>>>(Wq, Wk, Wv, wt);
  qkv_mfma_kernel<<<dim3(512), dim3(256), 0, stream>>>(x, wt, qb, kb, vt);
  attn_mfma_kernel<<<dim3(64, 8), dim3(256), 0, stream>>>(qb, kb, vt, out);
}